// Round 7
// baseline (12164.592 us; speedup 1.0000x reference)
//
#include <hip/hip_runtime.h>
#include <math.h>

#define T_SEQ 4096

__device__ __forceinline__ float sigmoidf_(float x) {
  return 1.0f / (1.0f + expf(-x));
}

__device__ __forceinline__ unsigned long long pack_h(int tag, float h) {
  return ((unsigned long long)(unsigned)tag << 32) |
         (unsigned long long)__float_as_uint(h);
}

// Exchange via atomic RMW: device-scope atomics are HW-coherent (m20) and
// CANNOT return stale data — they execute at the line's coherence point.
// R0-R6 showed plain cached probes always read stale lines and MALL-bypass
// probes cost a full memory RTT; atomics are the remaining mechanism that is
// both always-fresh and potentially L2-serviced.
__device__ __forceinline__ void st_a(unsigned long long* p, unsigned long long v) {
  atomicExch(p, v);   // result unused -> no-return encoding, fire-and-forget
}
__device__ __forceinline__ float poll_a(unsigned long long* p, unsigned want) {
  for (;;) {
    unsigned long long v = atomicOr(p, 0ull);   // RMW read, always coherent
    if ((unsigned)(v >> 32) == want) return __uint_as_float((unsigned)v);
  }
}

// Raw workgroup barrier: drains LDS (lgkmcnt) only — global publishes and
// prefetches stay in flight across it.
__device__ __forceinline__ void bar() {
  asm volatile("s_waitcnt lgkmcnt(0)" ::: "memory");
  __builtin_amdgcn_s_barrier();
  asm volatile("" ::: "memory");
}

// ---- named-register weight fragments + anti-rematerialization pin ----------
#define DECL_W8(p) float4 p##0, p##1, p##2, p##3, p##4, p##5, p##6, p##7
#define LOAD_W8(p, src) do { const float4* _s = (const float4*)(src); \
  p##0=_s[0]; p##1=_s[1]; p##2=_s[2]; p##3=_s[3]; \
  p##4=_s[4]; p##5=_s[5]; p##6=_s[6]; p##7=_s[7]; } while (0)
#define PIN4(v4) asm volatile("" : "+v"((v4).x), "+v"((v4).y), \
                                   "+v"((v4).z), "+v"((v4).w))
#define PIN_W8(p) do { PIN4(p##0); PIN4(p##1); PIN4(p##2); PIN4(p##3); \
  PIN4(p##4); PIN4(p##5); PIN4(p##6); PIN4(p##7); } while (0)
#define FMA4(acc, W_, H_) do { acc = fmaf((W_).x, (H_).x, acc); \
  acc = fmaf((W_).y, (H_).y, acc); acc = fmaf((W_).z, (H_).z, acc); \
  acc = fmaf((W_).w, (H_).w, acc); } while (0)
// acc += dot(p0..p7, h4[off..off+7])  (32 FMAs, one chain; 4 chains interleave)
#define G8(acc, p, off) do { \
  { float4 hv = h4[off + 0]; FMA4(acc, p##0, hv); } \
  { float4 hv = h4[off + 1]; FMA4(acc, p##1, hv); } \
  { float4 hv = h4[off + 2]; FMA4(acc, p##2, hv); } \
  { float4 hv = h4[off + 3]; FMA4(acc, p##3, hv); } \
  { float4 hv = h4[off + 4]; FMA4(acc, p##4, hv); } \
  { float4 hv = h4[off + 5]; FMA4(acc, p##5, hv); } \
  { float4 hv = h4[off + 6]; FMA4(acc, p##6, hv); } \
  { float4 hv = h4[off + 7]; FMA4(acc, p##7, hv); } \
} while (0)

// X[t][k] = emb[tokens[t]][k], as float4
__global__ void gather_emb(const int* __restrict__ tokens,
                           const float4* __restrict__ emb4,
                           float4* __restrict__ X4) {
  int i = blockIdx.x * 256 + threadIdx.x;   // i < 4096*128
  int t = i >> 7;
  int q = i & 127;
  X4[i] = emb4[(long)tokens[t] * 128 + q];
}

// P[t][j] = bias_ih[j] + bias_hh[j] + sum_k X[src(t)][k] * W[j][k]
__global__ __launch_bounds__(256) void gemm_proj(
    const float* __restrict__ Xf, const float* __restrict__ Xb, int revb,
    const float* __restrict__ Wf, const float* __restrict__ Wb,
    const float* __restrict__ bihf, const float* __restrict__ bhhf,
    const float* __restrict__ bihb, const float* __restrict__ bhhb,
    float* __restrict__ Pf, float* __restrict__ Pb, int K)
{
  const int dirb = blockIdx.z;
  const float* X  = dirb ? Xb : Xf;
  const float* W  = dirb ? Wb : Wf;
  const float* bih = dirb ? bihb : bihf;
  const float* bhh = dirb ? bhhb : bhhf;
  float* Pp = dirb ? Pb : Pf;
  const int rev = dirb ? revb : 0;

  const int bn = blockIdx.x;   // N tile (16)
  const int bm = blockIdx.y;   // M tile (64)
  const int tid = threadIdx.x;
  const int tx = tid & 15, ty = tid >> 4;

  __shared__ float Xs[16][68];
  __shared__ float Ws[16][68];

  float acc[4][4] = {{0.f}};

  const int lrow = tid >> 2;
  const int lk4  = (tid & 3) * 4;
  const int xrow = bm * 64 + lrow;
  const int xsrc = rev ? (4095 - xrow) : xrow;
  const float* xptr = X + (long)xsrc * K + lk4;
  const float* wptr = W + (long)(bn * 64 + lrow) * K + lk4;

  for (int k0 = 0; k0 < K; k0 += 16) {
    float4 xv = *(const float4*)(xptr + k0);
    float4 wv = *(const float4*)(wptr + k0);
    __syncthreads();
    Xs[lk4 + 0][lrow] = xv.x; Xs[lk4 + 1][lrow] = xv.y;
    Xs[lk4 + 2][lrow] = xv.z; Xs[lk4 + 3][lrow] = xv.w;
    Ws[lk4 + 0][lrow] = wv.x; Ws[lk4 + 1][lrow] = wv.y;
    Ws[lk4 + 2][lrow] = wv.z; Ws[lk4 + 3][lrow] = wv.w;
    __syncthreads();
    #pragma unroll
    for (int kk = 0; kk < 16; ++kk) {
      float4 a = *(const float4*)(&Xs[kk][ty * 4]);
      float4 b = *(const float4*)(&Ws[kk][tx * 4]);
      acc[0][0] = fmaf(a.x, b.x, acc[0][0]); acc[0][1] = fmaf(a.x, b.y, acc[0][1]);
      acc[0][2] = fmaf(a.x, b.z, acc[0][2]); acc[0][3] = fmaf(a.x, b.w, acc[0][3]);
      acc[1][0] = fmaf(a.y, b.x, acc[1][0]); acc[1][1] = fmaf(a.y, b.y, acc[1][1]);
      acc[1][2] = fmaf(a.y, b.z, acc[1][2]); acc[1][3] = fmaf(a.y, b.w, acc[1][3]);
      acc[2][0] = fmaf(a.z, b.x, acc[2][0]); acc[2][1] = fmaf(a.z, b.y, acc[2][1]);
      acc[2][2] = fmaf(a.z, b.z, acc[2][2]); acc[2][3] = fmaf(a.z, b.w, acc[2][3]);
      acc[3][0] = fmaf(a.w, b.x, acc[3][0]); acc[3][1] = fmaf(a.w, b.y, acc[3][1]);
      acc[3][2] = fmaf(a.w, b.z, acc[3][2]); acc[3][3] = fmaf(a.w, b.w, acc[3][3]);
    }
  }

  const int c0 = bn * 64 + tx * 4;
  #pragma unroll
  for (int i = 0; i < 4; ++i) {
    const int r = bm * 64 + ty * 4 + i;
    float4 o4;
    o4.x = acc[i][0] + bih[c0 + 0] + bhh[c0 + 0];
    o4.y = acc[i][1] + bih[c0 + 1] + bhh[c0 + 1];
    o4.z = acc[i][2] + bih[c0 + 2] + bhh[c0 + 2];
    o4.w = acc[i][3] + bih[c0 + 3] + bhh[c0 + 3];
    *(float4*)(&Pp[(long)r * 1024 + c0]) = o4;
  }
}

// Fused 2-layer bidirectional LSTM recurrence, restructured to ONE barrier
// per step:
//  - each ROW is covered by 2 (L0) / 4 (L1) lanes of the same wave; the
//    K-reduction is 1-2 shfl_xor, gate i/f/g/o combine stays in-wave ->
//    no part[] LDS round-trip, no second barrier, no serialized C phase.
//  - hx is parity double-buffered [2][512]: A(s+1) pollers write parity
//    (s+1)&1 while stragglers may still read parity s&1 -> race-free with a
//    single barrier.
//  - h-exchange via device-scope atomic RMW (st_a / poll_a above).
// Roles per direction (12): r 0-3 = L0 (64 cells), r 4-11 = L1 (32 cells).
__global__ __launch_bounds__(512, 1) void lstm_fused(
    const float* __restrict__ P0f, const float* __restrict__ P0b,
    const float* __restrict__ Whh0f, const float* __restrict__ Whh0b,
    const float* __restrict__ Wih1f, const float* __restrict__ Whh1f,
    const float* __restrict__ bih1f, const float* __restrict__ bhh1f,
    const float* __restrict__ Wih1b, const float* __restrict__ Whh1b,
    const float* __restrict__ bih1b, const float* __restrict__ bhh1b,
    float* __restrict__ out,
    unsigned long long* __restrict__ ring0,   // [2 dirs][4096][256]
    unsigned long long* __restrict__ h1x)     // [2 dirs][2 par][256]
{
  const int bx = blockIdx.x;
  const int t  = threadIdx.x;
  const int d   = bx & 1;    // 0 = forward, 1 = backward
  const int sub = bx >> 1;   // role within direction, 0..11

  __shared__ float hx2[2][512];   // parity-buffered h state

  unsigned long long* ring = ring0 + (long)d * T_SEQ * 256;

  if (sub < 4) {
    // ======================= Layer 0 (4 WGs/dir, 64 cells) ==================
    // t -> cell = t>>3 (0..63), gate = (t>>1)&3, kh = t&1 (k-half of 128).
    const int w = sub;
    const int wbase = w * 64;
    const float* __restrict__ P = d ? P0b : P0f;
    const float* __restrict__ W = d ? Whh0b : Whh0f;

    const int cell = t >> 3, gate = (t >> 1) & 3, kh = t & 1;
    const int j = gate * 256 + wbase + cell;   // global gate row

    DECL_W8(wa); DECL_W8(wb); DECL_W8(wc); DECL_W8(wd);
    const float* wsrc = W + (long)j * 256 + kh * 128;
    LOAD_W8(wa, wsrc); LOAD_W8(wb, wsrc + 32);
    LOAD_W8(wc, wsrc + 64); LOAD_W8(wd, wsrc + 96);
    PIN_W8(wa); PIN_W8(wb); PIN_W8(wc); PIN_W8(wd);

    float pv_cur = P[j];        // P[s=0][j]
    float c_prev = 0.0f;
    if (t < 256) hx2[0][t] = 0.0f;   // h(-1) = 0

    for (int s = 0; s < T_SEQ; ++s) {
      // -------- A: poll sibling h(s-1) into parity buffer s&1 --------------
      if (s > 0 && t < 192) {
        const int pcell = (t < wbase) ? t : t + 64;
        hx2[s & 1][pcell] = poll_a(ring + (long)(s - 1) * 256 + pcell,
                                   (unsigned)s);
      }
      float pv_next = 0.0f;
      if (s + 1 < T_SEQ) pv_next = P[(long)(s + 1) * 1024 + j];
      bar();   // hx2[s&1] complete (pollers + prev step's own-cell writes)

      // -------- B: matvec + in-wave reduce + act + combine + publish -------
      const float4* h4 = (const float4*)&hx2[s & 1][kh * 128];
      float a0 = 0.f, a1 = 0.f, a2 = 0.f, a3 = 0.f;
      G8(a0, wa, 0); G8(a1, wb, 8); G8(a2, wc, 16); G8(a3, wd, 24);
      float sum = (a0 + a1) + (a2 + a3);
      float tot = sum + __shfl_xor(sum, 1);          // join k-halves
      float g = pv_cur + tot;
      pv_cur = pv_next;
      float act = ((t & 6) == 4) ? tanhf(g) : sigmoidf_(g);   // gate==2
      float y  = __shfl_xor(act, 2);
      float zx = __shfl_xor(act, 4);
      float zy = __shfl_xor(y, 4);
      const bool l1b = (t & 2), h1b = (t & 4);
      float i_ = h1b ? (l1b ? zy : zx) : (l1b ? y : act);
      float f_ = h1b ? (l1b ? zx : zy) : (l1b ? act : y);
      float g_ = h1b ? (l1b ? y : act) : (l1b ? zy : zx);
      float o_ = h1b ? (l1b ? act : y) : (l1b ? zx : zy);
      float c = f_ * c_prev + i_ * g_;
      c_prev = c;
      float h = o_ * tanhf(c);
      if ((t & 7) == 0) {
        const int gc = wbase + cell;
        hx2[(s + 1) & 1][gc] = h;                 // own-cell LDS bypass
        st_a(ring + (long)s * 256 + gc, pack_h(s + 1, h));
        if (s == T_SEQ - 1) {
          out[d * 256 + gc] = c;            // cell_memories layer 0
          out[1024 + d * 256 + gc] = h;     // hidden_states layer 0
        }
      }
    }
  } else {
    // ======================= Layer 1 (8 WGs/dir, 32 cells) ==================
    // t -> cell = t>>4 (0..31), gate = (t>>2)&3, kq = t&3 (k-quarter of 128).
    const int w1 = sub - 4;
    const int wbase1 = w1 * 32;
    const float* __restrict__ Wih = d ? Wih1b : Wih1f;
    const float* __restrict__ Whh = d ? Whh1b : Whh1f;
    const float* __restrict__ bih = d ? bih1b : bih1f;
    const float* __restrict__ bhh = d ? bhh1b : bhh1f;
    unsigned long long* slot = h1x + d * 512;            // [parity][256]
    float* hout = d ? (out + 2048 + (long)4095 * 512 + 256) : (out + 2048);
    const long hstr = d ? -512 : 512;

    const int cell = t >> 4, gate = (t >> 2) & 3, kq = t & 3;
    const int j = gate * 256 + wbase1 + cell;   // global gate row

    DECL_W8(ua); DECL_W8(ub); DECL_W8(uc); DECL_W8(ud);
    const float* usrc = (kq < 2) ? (Wih + (long)j * 256 + kq * 128)
                                 : (Whh + (long)j * 256 + (kq - 2) * 128);
    LOAD_W8(ua, usrc); LOAD_W8(ub, usrc + 32);
    LOAD_W8(uc, usrc + 64); LOAD_W8(ud, usrc + 96);
    PIN_W8(ua); PIN_W8(ub); PIN_W8(uc); PIN_W8(ud);

    const float bsum = bih[j] + bhh[j];
    float c_prev = 0.0f;
    if ((t & 15) == 0) hx2[0][256 + wbase1 + cell] = 0.0f;  // own h1(-1)=0

    for (int s = 0; s < T_SEQ; ++s) {
      // -------- A: poll h0(s) (256) + sibling h1(s-1) (224) ----------------
      if (t < 256) {
        hx2[s & 1][t] = poll_a(ring + (long)s * 256 + t, (unsigned)(s + 1));
      } else if (t < 480) {
        const int q1 = t - 256;
        const int pc1 = (q1 < wbase1) ? q1 : q1 + 32;
        hx2[s & 1][256 + pc1] =
            poll_a(slot + ((s + 1) & 1) * 256 + pc1, (unsigned)s);
      }
      bar();   // hx2[s&1][0..511] complete

      // -------- B: matvec (K=512) + reduce + act + combine + publish -------
      const float4* h4 = (const float4*)&hx2[s & 1][kq * 128];
      float a0 = 0.f, a1 = 0.f, a2 = 0.f, a3 = 0.f;
      G8(a0, ua, 0); G8(a1, ub, 8); G8(a2, uc, 16); G8(a3, ud, 24);
      float sum = (a0 + a1) + (a2 + a3);
      float r1 = sum + __shfl_xor(sum, 1);           // join quarter pairs
      float r2 = r1 + __shfl_xor(r1, 2);             // full K sum
      float g = bsum + r2;
      float act = ((t & 12) == 8) ? tanhf(g) : sigmoidf_(g);  // gate==2
      float y  = __shfl_xor(act, 4);
      float zx = __shfl_xor(act, 8);
      float zy = __shfl_xor(y, 8);
      const bool l1b = (t & 4), h1b = (t & 8);
      float i_ = h1b ? (l1b ? zy : zx) : (l1b ? y : act);
      float f_ = h1b ? (l1b ? zx : zy) : (l1b ? act : y);
      float g_ = h1b ? (l1b ? y : act) : (l1b ? zy : zx);
      float o_ = h1b ? (l1b ? act : y) : (l1b ? zx : zy);
      float c = f_ * c_prev + i_ * g_;
      c_prev = c;
      float h = o_ * tanhf(c);
      if ((t & 15) == 0) {
        const int gc = wbase1 + cell;
        hx2[(s + 1) & 1][256 + gc] = h;              // own-cell LDS bypass
        st_a(&slot[(s & 1) * 256 + gc], pack_h(s + 1, h));
        hout[(long)s * hstr + gc] = h;
        if (s == T_SEQ - 1) {
          out[512 + d * 256 + gc] = c;          // cell_memories layer 1
          out[1024 + 512 + d * 256 + gc] = h;   // hidden_states layer 1
        }
      }
    }
  }
}

extern "C" void kernel_launch(void* const* d_in, const int* in_sizes, int n_in,
                              void* d_out, int out_size, void* d_ws, size_t ws_size,
                              hipStream_t stream) {
  const int*   tokens = (const int*)d_in[0];
  const float* emb    = (const float*)d_in[1];
  const float* fWih0 = (const float*)d_in[2];
  const float* fWhh0 = (const float*)d_in[3];
  const float* fbih0 = (const float*)d_in[4];
  const float* fbhh0 = (const float*)d_in[5];
  const float* fWih1 = (const float*)d_in[6];
  const float* fWhh1 = (const float*)d_in[7];
  const float* fbih1 = (const float*)d_in[8];
  const float* fbhh1 = (const float*)d_in[9];
  const float* bWih0 = (const float*)d_in[10];
  const float* bWhh0 = (const float*)d_in[11];
  const float* bbih0 = (const float*)d_in[12];
  const float* bbhh0 = (const float*)d_in[13];
  const float* bWih1 = (const float*)d_in[14];
  const float* bWhh1 = (const float*)d_in[15];
  const float* bbih1 = (const float*)d_in[16];
  const float* bbhh1 = (const float*)d_in[17];

  float* out = (float*)d_out;
  float* ws  = (float*)d_ws;

  // Workspace layout (float offsets):
  //   [0, 4194304)          h0 rings: [2 dirs][4096][256] u64 (16 MB).
  //                         X (4096x512, 8 MB) overlaps [0, 2097152) — dead
  //                         after gemm_proj; rings memset afterwards.
  //   [4194304,  8388608)   P0f (4096x1024)
  //   [8388608, 12582912)   P0b (4096x1024)
  //   [12582912, 12584960)  h1x: [2 dirs][2 par][256] u64 (8 KB)
  float* X   = ws;
  float* P0f = ws + 4194304;
  float* P0b = ws + 8388608;
  unsigned long long* ring0 = (unsigned long long*)ws;
  unsigned long long* h1x   = (unsigned long long*)(ws + 12582912);

  gather_emb<<<2048, 256, 0, stream>>>(tokens, (const float4*)emb, (float4*)X);

  // Layer 0 input projections (K=512); b-direction reads X time-reversed.
  gemm_proj<<<dim3(16, 64, 2), 256, 0, stream>>>(
      X, X, 1, fWih0, bWih0, fbih0, fbhh0, bbih0, bbhh0, P0f, P0b, 512);

  // Reset exchange buffers (tag 0 = "not ready" / "h[-1]=0").
  hipMemsetAsync(ring0, 0, (size_t)2 * T_SEQ * 256 * sizeof(unsigned long long), stream);
  hipMemsetAsync(h1x, 0, 1024 * sizeof(unsigned long long), stream);

  // Fused recurrence: 24 WGs (12 per direction), placement-independent.
  lstm_fused<<<dim3(24), 512, 0, stream>>>(
      P0f, P0b, fWhh0, bWhh0,
      fWih1, fWhh1, fbih1, fbhh1,
      bWih1, bWhh1, bbih1, bbhh1,
      out, ring0, h1x);
}